// Round 4
// baseline (87.243 us; speedup 1.0000x reference)
//
#include <hip/hip_runtime.h>

// Problem constants (fixed by the reference)
#define CIN      256
#define COUT     256
#define HWD      56
#define LSP      3136      // 56*56
#define BB       4
#define KDIM     2304      // CIN*9
#define NT       36        // KDIM/64
#define BLTOT    12544     // BB*LSP
#define NBX      49        // BLTOT/256
#define NTSB     (NT*NBX)  // 1764 tile-sum blocks

// ws layout (bytes):
//   [0      .. 1024)      scale      (256 f32)
//   [1024   .. 2048)      has_exc    (256 i32)
//   [2048   .. 38912)     cnt        (9216 i32)
//   [38912  .. 2398208)   exc        (9216*64 i32)
//   [2398208.. 4204544)   S          (451584 f32)  layout S[n*12544 + bl]
//   [4204544.. 4254720)   common_acc (12544 i32)   <- memsetAsync 0
#define OFF_SCALE   0
#define OFF_HASEXC  1024
#define OFF_CNT     2048
#define OFF_EXC     38912
#define OFF_S       2398208
#define OFF_COMMON  4204544

// D1 (after a 50KB memsetAsync zeroing common_acc): fused dispatch.
//  blocks [0, NTSB):      tile sum s = sum_{t<64} A[b,l,64n+t]  (t-ascending,
//                         fmaf(0/1,x,s) bit-exact); write S (exception path),
//                         quantize q_n = rint(clip(s/16)) and atomicAdd the
//                         INT into common_acc[bl] (integer sum is exact and
//                         order-independent -> replaces the old k_common).
//  blocks [NTSB, +COUT):  per-cout scale = mean|w| + sign-exception lists,
//                         self-zeroed cnt/has_exc.
__global__ __launch_bounds__(256)
void k_main(const float* __restrict__ x, const float* __restrict__ w,
            float* __restrict__ S, int* __restrict__ common_acc,
            float* __restrict__ scale, int* __restrict__ has_exc,
            int* __restrict__ cnt, int* __restrict__ exc) {
    int id  = blockIdx.x;
    int tid = threadIdx.x;
    if (id < NTSB) {
        int n  = id / NBX;                       // uniform
        int bl = (id - n * NBX) * 256 + tid;     // 0..12543
        int b  = bl / LSP;
        int l  = bl - b * LSP;
        int oh = l / HWD;
        int ow = l - oh * HWD;

        // 9 stencil offsets (clamped) + 0/1 masks, hoisted out of the k-loop.
        // Statically indexed -> stays in VGPRs.
        float m[9]; int off[9];
#pragma unroll
        for (int r = 0; r < 9; ++r) {
            int kh = r / 3, kw = r - 3 * (r / 3);      // compile-time
            int ih = oh - 1 + kh, iw = ow - 1 + kw;
            bool ok = ((unsigned)ih < (unsigned)HWD) & ((unsigned)iw < (unsigned)HWD);
            m[r]   = ok ? 1.f : 0.f;
            off[r] = ok ? (ih * HWD + iw) : 0;
        }

        int k0 = n * 64;
        int c0 = k0 / 9;              // uniform
        int r0 = k0 - 9 * c0;         // uniform, == (n*64) % 9
        const float* xc = x + (size_t)(b * CIN + c0) * LSP;

        float s = 0.f;
        // head: channel c0, r = r0..8 (uniform trip count)
#pragma unroll
        for (int r = 0; r < 9; ++r)
            if (r >= r0) s = fmaf(m[r], xc[off[r]], s);
        xc += LSP;
        // 6 full channels, static r
#pragma unroll
        for (int cc = 0; cc < 6; ++cc) {
#pragma unroll
            for (int r = 0; r < 9; ++r) s = fmaf(m[r], xc[off[r]], s);
            xc += LSP;
        }
        if (r0 == 8) {
            // 64 = 1 + 54 + 9: a 7th full channel, no tail
#pragma unroll
            for (int r = 0; r < 9; ++r) s = fmaf(m[r], xc[off[r]], s);
        } else {
            // tail: channel c0+7, r = 0..r0
#pragma unroll
            for (int r = 0; r < 9; ++r)
                if (r <= r0) s = fmaf(m[r], xc[off[r]], s);
        }
        S[n * BLTOT + bl] = s;                            // for exception path
        float ps = fminf(fmaxf(s * 0.0625f, -16.f), 15.f);
        atomicAdd(&common_acc[bl], (int)rintf(ps));       // exact int accumulate
    } else {
        int c = id - NTSB;
        // self-zero this block's slice
        if (tid < NT) cnt[c * NT + tid] = 0;
        if (tid == 0) has_exc[c] = 0;
        __syncthreads();

        const float* wr = w + c * KDIM;
        float s = 0.f;
#pragma unroll
        for (int i = 0; i < 9; ++i) {
            int k = i * 256 + tid;               // coalesced
            float v = wr[k];
            s += fabsf(v);
            int sg = (v > 0.f) - (v < 0.f);
            if (sg != 1) {                       // exception: contributes -mag*A
                int n  = k >> 6;
                int ti = k & 63;
                int mag = 1 - sg;                // 1 (zero w) or 2 (negative w)
                int idx = atomicAdd(&cnt[c * NT + n], 1);
                exc[(c * NT + n) * 64 + idx] = ti | (mag << 8);
                atomicOr(&has_exc[c], 1);
            }
        }
        __shared__ float red[256];
        red[tid] = s;
        __syncthreads();
#pragma unroll
        for (int o = 128; o > 0; o >>= 1) {
            if (tid < o) red[tid] += red[tid + o];
            __syncthreads();
        }
        if (tid == 0) scale[c] = red[0] * (1.f / (float)KDIM);
    }
}

// D2: out[b,c,l] = OA_8bit(common_acc[b,l]) * 16 * scale[c]; broadcast unless
// the channel has weight-sign exceptions (cold path: recompute from S).
__global__ __launch_bounds__(256)
void k_out(const float* __restrict__ x, const float* __restrict__ S,
           const int* __restrict__ common_acc, const float* __restrict__ scale,
           const int* __restrict__ has_exc, const int* __restrict__ cnt,
           const int* __restrict__ exc, float* __restrict__ out) {
    int gid = blockIdx.x * 256 + threadIdx.x;
    int o4 = gid * 4;                 // 4 consecutive outputs, same c (3136%4==0)
    int l = o4 % LSP;
    int t = o4 / LSP;                 // b*COUT + c
    int c = t & 255;
    int b = t >> 8;

    float sc = scale[c];
    float4 v;
    if (!has_exc[c]) {
        int4 a = *(const int4*)&common_acc[b * LSP + l];
        v.x = (float)((((a.x + 128) & 255) - 128) << 4);
        v.y = (float)((((a.y + 128) & 255) - 128) << 4);
        v.z = (float)((((a.z + 128) & 255) - 128) << 4);
        v.w = (float)((((a.w + 128) & 255) - 128) << 4);
    } else {
        float vv[4];
#pragma unroll
        for (int q = 0; q < 4; ++q) {
            int ll = l + q;
            int oh = ll / HWD, ow = ll - (ll / HWD) * HWD;
            int acc = 0;
            for (int n = 0; n < NT; ++n) {
                float ps = S[n * BLTOT + b * LSP + ll];
                int ct = cnt[c * NT + n];
                for (int e = 0; e < ct; ++e) {
                    int pk = exc[(c * NT + n) * 64 + e];
                    int ti = pk & 63;
                    int mag = pk >> 8;
                    int k = n * 64 + ti;
                    int ci = k / 9;
                    int r = k - 9 * ci;
                    int kh = r / 3;
                    int kw = r - 3 * kh;
                    int ih = oh - 1 + kh, iw = ow - 1 + kw;
                    float a = 0.f;
                    if ((unsigned)ih < (unsigned)HWD && (unsigned)iw < (unsigned)HWD)
                        a = x[(size_t)((b * CIN + ci) * HWD + ih) * HWD + iw];
                    ps -= (float)mag * a;
                }
                ps *= 0.0625f;
                ps = fminf(fmaxf(ps, -16.f), 15.f);
                acc += (int)rintf(ps);
            }
            int w8 = ((acc + 128) & 255) - 128;
            vv[q] = (float)(w8 << 4);
        }
        v = make_float4(vv[0], vv[1], vv[2], vv[3]);
    }
    v.x *= sc; v.y *= sc; v.z *= sc; v.w *= sc;
    *(float4*)&out[o4] = v;
}

extern "C" void kernel_launch(void* const* d_in, const int* in_sizes, int n_in,
                              void* d_out, int out_size, void* d_ws, size_t ws_size,
                              hipStream_t stream) {
    const float* x = (const float*)d_in[0];       // (4,256,56,56) f32
    const float* w = (const float*)d_in[1];       // (589824,1) f32
    float* out = (float*)d_out;                   // (4,256,56,56) f32

    char* ws = (char*)d_ws;
    float* scale      = (float*)(ws + OFF_SCALE);
    int*   has_exc    = (int*)  (ws + OFF_HASEXC);
    int*   cnt        = (int*)  (ws + OFF_CNT);
    int*   exc        = (int*)  (ws + OFF_EXC);
    float* S          = (float*)(ws + OFF_S);
    int*   common_acc = (int*)  (ws + OFF_COMMON);

    hipMemsetAsync(common_acc, 0, BLTOT * sizeof(int), stream);   // 50 KB
    k_main<<<NTSB + COUT, 256, 0, stream>>>(x, w, S, common_acc,
                                            scale, has_exc, cnt, exc);
    k_out<<<(BB * COUT * LSP) / (4 * 256), 256, 0, stream>>>(
        x, S, common_acc, scale, has_exc, cnt, exc, out);
}

// Round 5
// 85.434 us; speedup vs baseline: 1.0212x; 1.0212x over previous
//
#include <hip/hip_runtime.h>

// Problem constants (fixed by the reference)
#define CIN      256
#define COUT     256
#define HWD      56
#define LSP      3136      // 56*56
#define BB       4
#define KDIM     2304      // CIN*9
#define NT       36        // KDIM/64
#define BLTOT    12544     // BB*LSP
#define NBX      49        // BLTOT/256
#define NTSB     (NT*NBX)  // 1764 tile-sum blocks
#define PPB      32        // pixels per k_out2 block (LSP%32==0, no b-crossing)

// ws layout (bytes):
//   [0      .. 1024)      scale      (256 f32)
//   [1024   .. 2048)      has_exc    (256 i32)
//   [2048   .. 38912)     cnt        (9216 i32)
//   [38912  .. 2398208)   exc        (9216*64 i32)
//   [2398208.. 4204544)   S          (451584 f32)  layout S[n*12544 + bl]
#define OFF_SCALE   0
#define OFF_HASEXC  1024
#define OFF_CNT     2048
#define OFF_EXC     38912
#define OFF_S       2398208

// D1: fused dispatch (no memset, no atomics to global accumulators).
//  blocks [0, NTSB):      tile sums S[n*BLTOT + bl] = sum_{t<64} A[b,l,64n+t]
//                         (t-ascending adds; fmaf(0/1,x,s) bit-exact)
//  blocks [NTSB, +COUT):  per-cout scale = mean|w| + sign-exception lists,
//                         self-zeroed cnt/has_exc.
__global__ __launch_bounds__(256)
void k_main(const float* __restrict__ x, const float* __restrict__ w,
            float* __restrict__ S, float* __restrict__ scale,
            int* __restrict__ has_exc, int* __restrict__ cnt,
            int* __restrict__ exc) {
    int id  = blockIdx.x;
    int tid = threadIdx.x;
    if (id < NTSB) {
        int n  = id / NBX;                       // uniform
        int bl = (id - n * NBX) * 256 + tid;     // 0..12543
        int b  = bl / LSP;
        int l  = bl - b * LSP;
        int oh = l / HWD;
        int ow = l - oh * HWD;

        // 9 stencil offsets (clamped) + 0/1 masks, hoisted; statically indexed.
        float m[9]; int off[9];
#pragma unroll
        for (int r = 0; r < 9; ++r) {
            int kh = r / 3, kw = r - 3 * (r / 3);      // compile-time
            int ih = oh - 1 + kh, iw = ow - 1 + kw;
            bool ok = ((unsigned)ih < (unsigned)HWD) & ((unsigned)iw < (unsigned)HWD);
            m[r]   = ok ? 1.f : 0.f;
            off[r] = ok ? (ih * HWD + iw) : 0;
        }

        int k0 = n * 64;
        int c0 = k0 / 9;              // uniform
        int r0 = k0 - 9 * c0;         // uniform, == (n*64) % 9
        const float* xc = x + (size_t)(b * CIN + c0) * LSP;

        float s = 0.f;
#pragma unroll
        for (int r = 0; r < 9; ++r)            // head: channel c0, r0..8
            if (r >= r0) s = fmaf(m[r], xc[off[r]], s);
        xc += LSP;
#pragma unroll
        for (int cc = 0; cc < 6; ++cc) {       // 6 full channels
#pragma unroll
            for (int r = 0; r < 9; ++r) s = fmaf(m[r], xc[off[r]], s);
            xc += LSP;
        }
        if (r0 == 8) {                         // 64 = 1+54+9: 7th full channel
#pragma unroll
            for (int r = 0; r < 9; ++r) s = fmaf(m[r], xc[off[r]], s);
        } else {                               // tail: channel c0+7, 0..r0
#pragma unroll
            for (int r = 0; r < 9; ++r)
                if (r <= r0) s = fmaf(m[r], xc[off[r]], s);
        }
        S[n * BLTOT + bl] = s;
    } else {
        int c = id - NTSB;
        if (tid < NT) cnt[c * NT + tid] = 0;   // self-zero (replaces memset)
        if (tid == 0) has_exc[c] = 0;
        __syncthreads();

        const float* wr = w + c * KDIM;
        float s = 0.f;
#pragma unroll
        for (int i = 0; i < 9; ++i) {
            int k = i * 256 + tid;             // coalesced
            float v = wr[k];
            s += fabsf(v);
            int sg = (v > 0.f) - (v < 0.f);
            if (sg != 1) {                     // exception: contributes -mag*A
                int n  = k >> 6;
                int ti = k & 63;
                int mag = 1 - sg;              // 1 (zero w) or 2 (negative w)
                int idx = atomicAdd(&cnt[c * NT + n], 1);
                exc[(c * NT + n) * 64 + idx] = ti | (mag << 8);
                atomicOr(&has_exc[c], 1);
            }
        }
        __shared__ float red[256];
        red[tid] = s;
        __syncthreads();
#pragma unroll
        for (int o = 128; o > 0; o >>= 1) {
            if (tid < o) red[tid] += red[tid + o];
            __syncthreads();
        }
        if (tid == 0) scale[c] = red[0] * (1.f / (float)KDIM);
    }
}

// D2: one block per 32 pixels. Load the 32x36 S panel once, quantize,
// per-pixel integer reduce in LDS (lane p walks bank p: conflict-free),
// OA wraparound, then broadcast to all 256 channels with float4 stores.
__global__ __launch_bounds__(256)
void k_out2(const float* __restrict__ x, const float* __restrict__ S,
            const float* __restrict__ scale, const int* __restrict__ has_exc,
            const int* __restrict__ cnt, const int* __restrict__ exc,
            float* __restrict__ out) {
    __shared__ int   q[NT][PPB];      // quantized tile values
    __shared__ float cv[PPB];         // common output value per pixel
    __shared__ float sscale[COUT];
    __shared__ int   she[COUT];

    int t   = threadIdx.x;
    int bl0 = blockIdx.x * PPB;       // 32-aligned; LSP%32==0 -> single b
    int b   = bl0 / LSP;
    int l0  = bl0 - b * LSP;

    sscale[t] = scale[t];
    she[t]    = has_exc[t];

    int p  = t & 31;
    int nb = t >> 5;                  // 0..7
#pragma unroll
    for (int i = 0; i < 5; ++i) {
        int nn = nb + 8 * i;
        if (nn < NT) {                // i==4: only nb<4
            float ps = S[nn * BLTOT + bl0 + p] * 0.0625f;   // coalesced
            ps = fminf(fmaxf(ps, -16.f), 15.f);
            q[nn][p] = (int)rintf(ps);
        }
    }
    __syncthreads();
    if (t < PPB) {
        int acc = 0;
#pragma unroll
        for (int n = 0; n < NT; ++n) acc += q[n][t];        // exact int sum
        int w8 = ((acc + 128) & 255) - 128;                 // OA wraparound
        cv[t] = (float)(w8 << 4);                           // *2^shift
    }
    __syncthreads();

    // 8 iterations: c = t/8 + 32*cc, 4 pixels per thread via float4.
#pragma unroll
    for (int cc = 0; cc < 8; ++cc) {
        int c  = (t >> 3) + 32 * cc;
        int p4 = (t & 7) * 4;
        float sc = sscale[c];
        float4 v;
        if (!she[c]) {
            v = make_float4(cv[p4], cv[p4 + 1], cv[p4 + 2], cv[p4 + 3]);
        } else {
            // cold path: recompute with weight-sign corrections
            float vv[4];
#pragma unroll
            for (int j = 0; j < 4; ++j) {
                int ll = l0 + p4 + j;
                int oh = ll / HWD, ow = ll - (ll / HWD) * HWD;
                int acc = 0;
                for (int n = 0; n < NT; ++n) {
                    float ps = S[n * BLTOT + b * LSP + ll];
                    int ct = cnt[c * NT + n];
                    for (int e = 0; e < ct; ++e) {
                        int pk = exc[(c * NT + n) * 64 + e];
                        int ti = pk & 63;
                        int mag = pk >> 8;
                        int k = n * 64 + ti;
                        int ci = k / 9;
                        int r  = k - 9 * ci;
                        int kh = r / 3;
                        int kw = r - 3 * kh;
                        int ih = oh - 1 + kh, iw = ow - 1 + kw;
                        float a = 0.f;
                        if ((unsigned)ih < (unsigned)HWD && (unsigned)iw < (unsigned)HWD)
                            a = x[(size_t)((b * CIN + ci) * HWD + ih) * HWD + iw];
                        ps -= (float)mag * a;
                    }
                    ps *= 0.0625f;
                    ps = fminf(fmaxf(ps, -16.f), 15.f);
                    acc += (int)rintf(ps);
                }
                int w8 = ((acc + 128) & 255) - 128;
                vv[j] = (float)(w8 << 4);
            }
            v = make_float4(vv[0], vv[1], vv[2], vv[3]);
        }
        v.x *= sc; v.y *= sc; v.z *= sc; v.w *= sc;
        *(float4*)&out[(size_t)(b * COUT + c) * LSP + l0 + p4] = v;
    }
}

extern "C" void kernel_launch(void* const* d_in, const int* in_sizes, int n_in,
                              void* d_out, int out_size, void* d_ws, size_t ws_size,
                              hipStream_t stream) {
    const float* x = (const float*)d_in[0];       // (4,256,56,56) f32
    const float* w = (const float*)d_in[1];       // (589824,1) f32
    float* out = (float*)d_out;                   // (4,256,56,56) f32

    char* ws = (char*)d_ws;
    float* scale   = (float*)(ws + OFF_SCALE);
    int*   has_exc = (int*)  (ws + OFF_HASEXC);
    int*   cnt     = (int*)  (ws + OFF_CNT);
    int*   exc     = (int*)  (ws + OFF_EXC);
    float* S       = (float*)(ws + OFF_S);

    k_main<<<NTSB + COUT, 256, 0, stream>>>(x, w, S, scale, has_exc, cnt, exc);
    k_out2<<<BLTOT / PPB, 256, 0, stream>>>(x, S, scale, has_exc, cnt, exc, out);
}